// Round 12
// baseline (1862.882 us; speedup 1.0000x reference)
//
#include <hip/hip_runtime.h>
#include <hip/hip_bf16.h>
#include <stdint.h>
#include <math.h>

// ---------------- types / helpers ----------------
typedef __attribute__((ext_vector_type(8))) short bf16x8;   // 8 bf16 in 4 VGPRs
typedef __attribute__((ext_vector_type(4))) float f32x4;

#define AS1 __attribute__((address_space(1)))
#define AS3 __attribute__((address_space(3)))

__device__ __forceinline__ ushort f2bf(float f) {
  union { float f; uint32_t u; } in; in.f = f;
  uint32_t u = in.u;
  uint32_t r = u + 0x7fffu + ((u >> 16) & 1u);   // RNE; inputs finite
  return (ushort)(r >> 16);
}
__device__ __forceinline__ float bf2f(ushort h) {
  union { uint32_t u; float f; } out; out.u = ((uint32_t)h) << 16;
  return out.f;
}

// ---------------- cast f32 -> bf16 (vectorized) ----------------
__global__ __launch_bounds__(256)
void cast_f32_bf16(const float4* __restrict__ in, ushort4* __restrict__ out, int n4) {
  int i = blockIdx.x * blockDim.x + threadIdx.x;
  int stride = gridDim.x * blockDim.x;
  for (; i < n4; i += stride) {
    float4 v = in[i];
    ushort4 o;
    o.x = f2bf(v.x); o.y = f2bf(v.y); o.z = f2bf(v.z); o.w = f2bf(v.w);
    out[i] = o;
  }
}

// ---------------- V (B,LK,D) f32 -> Vt (B,D,LK) bf16 ----------------
__global__ __launch_bounds__(256)
void transpose_cast_v(const float* __restrict__ V, ushort* __restrict__ Vt) {
  __shared__ ushort tile[32][33];                // +1 pad: no bank conflicts
  const int b  = blockIdx.z;
  const int k0 = blockIdx.x * 32;
  const int d0 = blockIdx.y * 32;
  const int tx = threadIdx.x;                    // 0..31
  const int ty = threadIdx.y;                    // 0..7
  const float* Vb = V + ((size_t)b * 1024 + k0) * 1024 + d0;
  #pragma unroll
  for (int r = 0; r < 4; ++r) {
    int k = ty * 4 + r;
    tile[k][tx] = f2bf(Vb[(size_t)k * 1024 + tx]);
  }
  __syncthreads();
  ushort* Vtb = Vt + ((size_t)b * 1024 + d0) * 1024 + k0;
  #pragma unroll
  for (int r = 0; r < 4; ++r) {
    int d = ty * 4 + r;
    Vtb[(size_t)d * 1024 + tx] = tile[tx][d];
  }
}

// ---------------- masked softmax over each (b,q) row of S (bf16 in/out) ----
__global__ __launch_bounds__(256)
void softmax_mask(const ushort* __restrict__ S, ushort* __restrict__ P,
                  const float* __restrict__ mask) {
  const int rowId = blockIdx.x;                  // 0..B*LQ-1
  const int b = rowId >> 10;                     // LQ = 1024
  const ushort4* srow = (const ushort4*)(S + (size_t)rowId * 1024);
  const float4* mrow = (const float4*)(mask + (size_t)b * 1024);
  const int t = threadIdx.x;
  const int wid = t >> 6, lane = t & 63;

  ushort4 sv = srow[t];
  float4 mv = mrow[t];
  float s[4] = {bf2f(sv.x), bf2f(sv.y), bf2f(sv.z), bf2f(sv.w)};
  float m[4] = {mv.x, mv.y, mv.z, mv.w};

  float mx = -INFINITY;
  #pragma unroll
  for (int i = 0; i < 4; ++i) if (m[i] != 0.f) mx = fmaxf(mx, s[i]);
  #pragma unroll
  for (int off = 32; off > 0; off >>= 1)
    mx = fmaxf(mx, __shfl_xor(mx, off));

  __shared__ float wred[4][2];
  if (lane == 0) wred[wid][0] = mx;
  __syncthreads();
  float M = fmaxf(fmaxf(wred[0][0], wred[1][0]), fmaxf(wred[2][0], wred[3][0]));

  float e[4]; float sum = 0.f;
  #pragma unroll
  for (int i = 0; i < 4; ++i) {
    e[i] = (m[i] != 0.f) ? __expf(s[i] - M) : 0.f;
    sum += e[i];
  }
  #pragma unroll
  for (int off = 32; off > 0; off >>= 1)
    sum += __shfl_xor(sum, off);
  if (lane == 0) wred[wid][1] = sum;
  __syncthreads();
  float Z = wred[0][1] + wred[1][1] + wred[2][1] + wred[3][1];
  float inv = (Z > 0.f) ? 1.f / Z : 0.f;

  ushort4 o;
  o.x = f2bf(e[0] * inv); o.y = f2bf(e[1] * inv);
  o.z = f2bf(e[2] * inv); o.w = f2bf(e[3] * inv);
  ((ushort4*)(P + (size_t)rowId * 1024))[t] = o;
}

// ---------------- GEMM 256x256, BK=64, 8 waves, single-buffer -------------
// C = A(Mx1024,row) * Bt(1024x1024,row)^T.
// r9's counters showed 128^2/4-blk at the per-CU staging-BW wall (52 B/cyc).
// Fix = arithmetic intensity: 256^2 tile stages 64 KB per kt for 8.39 MFLOP
// (131 FLOP/B, 2x the 128^2 tile).  SINGLE-buffered 64 KiB LDS -> 2 blocks/CU
// (r3's 256^2 failed only because 128 KiB dbuf forced 1 block/CU).
// Per epoch (2 blocks x 1 kt): MFMA 4096 cyc/SIMD > staging ~2460 cyc -> BW
// hideable.  No inline asm (r9-style): compiler emits vmcnt/lgkm drains at
// __syncthreads.
// + T2 swizzle: byte involution y ^= (y>>3)&0x70 (rule #21 pairing);
//   0 bank conflicts measured on this exact read pattern (r6-r9).
// + T1 XCD remap (all grids here are multiples of 8).
// EPI: 0 -> outBf = bf16(acc*scale)                              (S)
//      1 -> outBf = bf16(bf2f(auxBf) + acc)                      (X = Q + PV)
//      2 -> outBf = bf16(relu(acc + bias[col]))                  (FFN1 -> h)
//      3 -> outF  = acc + bias[col] + bf2f(auxBf)                (FFN2 + residual)
template<int EPI>
__global__ __launch_bounds__(512, 4)
void gemm256(const ushort* __restrict__ A, const ushort* __restrict__ Bt,
             size_t aBatch, size_t bBatch, size_t oBatch,
             float scale,
             ushort* outBf, float* outF, const ushort* auxBf,
             const float* __restrict__ bias)
{
  constexpr int K = 1024, N = 1024, NT = 16;    // K-tiles of 64
  __shared__ ushort lds[2][16384];              // [A=0,B=1][256*64] = 64 KiB
  const int t = threadIdx.x;
  const int w = t >> 6, lane = t & 63;
  const int wr = w >> 2, wc = w & 3;            // 2 x 4 waves -> 128x64 per wave
  const int lr16 = lane & 15, kg = lane >> 4;

  // T1: XCD-aware bijective remap (nwg is a multiple of 8 for all our grids)
  const unsigned nx = gridDim.x, ny = gridDim.y;
  unsigned flat = blockIdx.x + nx * (blockIdx.y + ny * blockIdx.z);
  const unsigned nwg = nx * ny * gridDim.z;
  const unsigned cpx = nwg >> 3;
  unsigned nf = (flat & 7u) * cpx + (flat >> 3);
  const unsigned bxi = nf % nx;
  const unsigned rest = nf / nx;
  const unsigned byi = rest % ny;
  const unsigned bz = rest / ny;
  const int m0 = byi * 256, n0 = bxi * 256;

  const char* Ab = (const char*)(A + (size_t)bz * aBatch + (size_t)m0 * K);
  const char* Bb = (const char*)(Bt + (size_t)bz * bBatch + (size_t)n0 * K);

  // staging decode: 4 chunks of 16B/lane per matrix per thread (32 KiB tile).
  // lds-linear byte y = (w*4+i)*1024 + lane*16; unswizzled tile byte
  // tb = y ^ ((y>>3)&0x70); global = (tb>>7)*2048 + (tb&127) + kt*128.
  int gOff[4], lOff[4];
  #pragma unroll
  for (int i = 0; i < 4; ++i) {
    int y = (w * 4 + i) * 1024 + lane * 16;
    int tb = y ^ ((y >> 3) & 0x70);
    gOff[i] = (tb >> 7) * 2048 + (tb & 127);
    lOff[i] = (w * 4 + i) * 1024;               // wave-uniform LDS base (+lane*16 by HW)
  }

  // fragment reads (swizzled): row*128 + ((ks*4+kg)^(row&7))*16, row&7 = lr16&7
  const int sl0 = (kg ^ (lr16 & 7)) << 4;
  const int aBase = (wr * 128 + lr16) * 128 + sl0;
  const int bBase = (wc * 64 + lr16) * 128 + sl0;

  f32x4 acc[8][4];
  #pragma unroll
  for (int i = 0; i < 8; ++i)
    #pragma unroll
    for (int j = 0; j < 4; ++j)
      acc[i][j] = (f32x4){0.f, 0.f, 0.f, 0.f};

  #pragma unroll 1
  for (int kt = 0; kt < NT; ++kt) {
    // stage tile kt into the single buffer (4+4 gload_lds w=16 per thread)
    #pragma unroll
    for (int i = 0; i < 4; ++i)
      __builtin_amdgcn_global_load_lds(
        (const AS1 void*)(Ab + gOff[i] + kt * 128),
        (AS3 void*)((char*)&lds[0][0] + lOff[i]), 16, 0, 0);
    #pragma unroll
    for (int i = 0; i < 4; ++i)
      __builtin_amdgcn_global_load_lds(
        (const AS1 void*)(Bb + gOff[i] + kt * 128),
        (AS3 void*)((char*)&lds[1][0] + lOff[i]), 16, 0, 0);
    __syncthreads();                            // compiler: vmcnt(0) drain

    #pragma unroll
    for (int ks = 0; ks < 2; ++ks) {
      bf16x8 af[8], bfv[4];
      #pragma unroll
      for (int mi = 0; mi < 8; ++mi)
        af[mi] = *(const bf16x8*)((const char*)&lds[0][0] + ((aBase + mi * 2048) ^ (ks * 64)));
      #pragma unroll
      for (int ni = 0; ni < 4; ++ni)
        bfv[ni] = *(const bf16x8*)((const char*)&lds[1][0] + ((bBase + ni * 2048) ^ (ks * 64)));
      #pragma unroll
      for (int mi = 0; mi < 8; ++mi)
        #pragma unroll
        for (int ni = 0; ni < 4; ++ni)
          acc[mi][ni] = __builtin_amdgcn_mfma_f32_16x16x32_bf16(
              af[mi], bfv[ni], acc[mi][ni], 0, 0, 0);
    }
    __syncthreads();                            // reads drained before re-stage
  }

  // epilogue: C/D layout col=lane&15, row=(lane>>4)*4+j  [m89-verified]
  const int lr4 = kg * 4;
  #pragma unroll
  for (int mi = 0; mi < 8; ++mi) {
    #pragma unroll
    for (int ni = 0; ni < 4; ++ni) {
      int row = m0 + wr * 128 + mi * 16 + lr4;
      int col = n0 + wc * 64 + ni * 16 + lr16;
      size_t o = (size_t)bz * oBatch + (size_t)row * N + col;
      f32x4 v = acc[mi][ni];
      #pragma unroll
      for (int j = 0; j < 4; ++j) {
        size_t oo = o + (size_t)j * N;
        float x = v[j];
        if (EPI == 0) {
          outBf[oo] = f2bf(x * scale);
        } else if (EPI == 1) {
          outBf[oo] = f2bf(bf2f(auxBf[oo]) + x);
        } else if (EPI == 2) {
          float h = x + bias[col];
          h = h > 0.f ? h : 0.f;
          outBf[oo] = f2bf(h);
        } else {
          outF[oo] = x + bias[col] + bf2f(auxBf[oo]);
        }
      }
    }
  }
}

// ---------------- launch ----------------
extern "C" void kernel_launch(void* const* d_in, const int* in_sizes, int n_in,
                              void* d_out, int out_size, void* d_ws, size_t ws_size,
                              hipStream_t stream) {
  (void)in_sizes; (void)n_in; (void)out_size; (void)ws_size;
  const float* Q  = (const float*)d_in[0];
  const float* Km = (const float*)d_in[1];
  const float* V  = (const float*)d_in[2];
  const float* Vm = (const float*)d_in[3];
  const float* W1 = (const float*)d_in[4];
  const float* b1 = (const float*)d_in[5];
  const float* W2 = (const float*)d_in[6];
  const float* b2 = (const float*)d_in[7];
  float* out = (float*)d_out;

  const int LQ = 1024, LK = 1024, D = 1024;
  const size_t NQ = (size_t)32 * LQ * D;            // 33.5M elems

  // workspace layout (MiB offsets): Qb 0..64, Kb/hb 64..128, Vt 128..192,
  // Sb 192..256, P 256..320, Xb 320..384, W1b 384..386, W2b 386..388
  char* ws = (char*)d_ws;
  ushort* Qb  = (ushort*)(ws);
  ushort* Kb  = (ushort*)(ws + ((size_t)64 << 20));
  ushort* hb  = Kb;                                  // reuse (Kb dead after S-GEMM)
  ushort* Vt  = (ushort*)(ws + ((size_t)128 << 20));
  ushort* Sb  = (ushort*)(ws + ((size_t)192 << 20));
  ushort* P   = (ushort*)(ws + ((size_t)256 << 20));
  ushort* Xb  = (ushort*)(ws + ((size_t)320 << 20));
  ushort* W1b = (ushort*)(ws + ((size_t)384 << 20));
  ushort* W2b = (ushort*)(ws + ((size_t)386 << 20));

  const float inv_scale = 1.0f / (sqrtf(1024.0f) + 1e-8f);

  cast_f32_bf16<<<2048, 256, 0, stream>>>((const float4*)Q,  (ushort4*)Qb, (int)(NQ / 4));
  cast_f32_bf16<<<2048, 256, 0, stream>>>((const float4*)Km, (ushort4*)Kb, (int)(NQ / 4));
  cast_f32_bf16<<<256, 256, 0, stream>>>((const float4*)W1, (ushort4*)W1b, (1024 * 1024) / 4);
  cast_f32_bf16<<<256, 256, 0, stream>>>((const float4*)W2, (ushort4*)W2b, (1024 * 1024) / 4);
  transpose_cast_v<<<dim3(32, 32, 32), dim3(32, 8), 0, stream>>>(V, Vt);

  // Sb = bf16((Qb @ Kb^T) * inv_scale), batched over 32
  gemm256<0><<<dim3(4, 4, 32), 512, 0, stream>>>(
      Qb, Kb,
      (size_t)LQ * D, (size_t)LK * D, (size_t)LQ * LK,
      inv_scale, Sb, nullptr, nullptr, nullptr);

  softmax_mask<<<32768, 256, 0, stream>>>(Sb, P, Vm);

  // Xb = bf16(Qb + P @ V)
  gemm256<1><<<dim3(4, 4, 32), 512, 0, stream>>>(
      P, Vt,
      (size_t)LQ * LK, (size_t)D * LK, (size_t)LQ * D,
      1.f, Xb, nullptr, Qb, nullptr);

  // hb = bf16(relu(Xb @ W1^T + b1)); M = 32768 folded into blockIdx.y
  gemm256<2><<<dim3(4, 128, 1), 512, 0, stream>>>(
      Xb, W1b, 0, 0, 0,
      1.f, hb, nullptr, nullptr, b1);

  // out = hb @ W2^T + b2 + Xb
  gemm256<3><<<dim3(4, 128, 1), 512, 0, stream>>>(
      hb, W2b, 0, 0, 0,
      1.f, nullptr, out, Xb, b2);
}

// Round 13
// 556.314 us; speedup vs baseline: 3.3486x; 3.3486x over previous
//
#include <hip/hip_runtime.h>
#include <hip/hip_bf16.h>
#include <stdint.h>
#include <math.h>

// ---------------- types / helpers ----------------
typedef __attribute__((ext_vector_type(8))) short bf16x8;   // 8 bf16 in 4 VGPRs
typedef __attribute__((ext_vector_type(4))) float f32x4;

#define AS1 __attribute__((address_space(1)))
#define AS3 __attribute__((address_space(3)))

__device__ __forceinline__ ushort f2bf(float f) {
  union { float f; uint32_t u; } in; in.f = f;
  uint32_t u = in.u;
  uint32_t r = u + 0x7fffu + ((u >> 16) & 1u);   // RNE; inputs finite
  return (ushort)(r >> 16);
}
__device__ __forceinline__ float bf2f(ushort h) {
  union { uint32_t u; float f; } out; out.u = ((uint32_t)h) << 16;
  return out.f;
}

// ---------------- cast f32 -> bf16 (vectorized) ----------------
__global__ __launch_bounds__(256)
void cast_f32_bf16(const float4* __restrict__ in, ushort4* __restrict__ out, int n4) {
  int i = blockIdx.x * blockDim.x + threadIdx.x;
  int stride = gridDim.x * blockDim.x;
  for (; i < n4; i += stride) {
    float4 v = in[i];
    ushort4 o;
    o.x = f2bf(v.x); o.y = f2bf(v.y); o.z = f2bf(v.z); o.w = f2bf(v.w);
    out[i] = o;
  }
}

// ---------------- V (B,LK,D) f32 -> Vt (B,D,LK) bf16 ----------------
__global__ __launch_bounds__(256)
void transpose_cast_v(const float* __restrict__ V, ushort* __restrict__ Vt) {
  __shared__ ushort tile[32][33];                // +1 pad: no bank conflicts
  const int b  = blockIdx.z;
  const int k0 = blockIdx.x * 32;
  const int d0 = blockIdx.y * 32;
  const int tx = threadIdx.x;                    // 0..31
  const int ty = threadIdx.y;                    // 0..7
  const float* Vb = V + ((size_t)b * 1024 + k0) * 1024 + d0;
  #pragma unroll
  for (int r = 0; r < 4; ++r) {
    int k = ty * 4 + r;
    tile[k][tx] = f2bf(Vb[(size_t)k * 1024 + tx]);
  }
  __syncthreads();
  ushort* Vtb = Vt + ((size_t)b * 1024 + d0) * 1024 + k0;
  #pragma unroll
  for (int r = 0; r < 4; ++r) {
    int d = ty * 4 + r;
    Vtb[(size_t)d * 1024 + tx] = tile[tx][d];
  }
}

// ---------------- masked softmax over each (b,q) row of S (bf16 in/out) ----
__global__ __launch_bounds__(256)
void softmax_mask(const ushort* __restrict__ S, ushort* __restrict__ P,
                  const float* __restrict__ mask) {
  const int rowId = blockIdx.x;                  // 0..B*LQ-1
  const int b = rowId >> 10;                     // LQ = 1024
  const ushort4* srow = (const ushort4*)(S + (size_t)rowId * 1024);
  const float4* mrow = (const float4*)(mask + (size_t)b * 1024);
  const int t = threadIdx.x;
  const int wid = t >> 6, lane = t & 63;

  ushort4 sv = srow[t];
  float4 mv = mrow[t];
  float s[4] = {bf2f(sv.x), bf2f(sv.y), bf2f(sv.z), bf2f(sv.w)};
  float m[4] = {mv.x, mv.y, mv.z, mv.w};

  float mx = -INFINITY;
  #pragma unroll
  for (int i = 0; i < 4; ++i) if (m[i] != 0.f) mx = fmaxf(mx, s[i]);
  #pragma unroll
  for (int off = 32; off > 0; off >>= 1)
    mx = fmaxf(mx, __shfl_xor(mx, off));

  __shared__ float wred[4][2];
  if (lane == 0) wred[wid][0] = mx;
  __syncthreads();
  float M = fmaxf(fmaxf(wred[0][0], wred[1][0]), fmaxf(wred[2][0], wred[3][0]));

  float e[4]; float sum = 0.f;
  #pragma unroll
  for (int i = 0; i < 4; ++i) {
    e[i] = (m[i] != 0.f) ? __expf(s[i] - M) : 0.f;
    sum += e[i];
  }
  #pragma unroll
  for (int off = 32; off > 0; off >>= 1)
    sum += __shfl_xor(sum, off);
  if (lane == 0) wred[wid][1] = sum;
  __syncthreads();
  float Z = wred[0][1] + wred[1][1] + wred[2][1] + wred[3][1];
  float inv = (Z > 0.f) ? 1.f / Z : 0.f;

  ushort4 o;
  o.x = f2bf(e[0] * inv); o.y = f2bf(e[1] * inv);
  o.z = f2bf(e[2] * inv); o.w = f2bf(e[3] * inv);
  ((ushort4*)(P + (size_t)rowId * 1024))[t] = o;
}

// ---------------- GEMM 256x256, BK=64, 8 waves, m201 8-phase schedule -----
// C = A(Mx1024,row) * Bt(1024x1024,row)^T.  Faithful m201 template:
// - half-tile = K-half (256 rows x 32 K = 16 KB, 2 gload_lds/thread)
// - LDS [2 buf][A,B][2 ksHalf][256 rows x 32 K], buf0=even kt, buf1=odd
// - 8 phases per iter (2 K-tiles); phase = {ds_read 4-or-8 b128 ; stage 1
//   half-tile ; barrier ; lgkmcnt(0)+sched_barrier ; setprio(1) ; 16 MFMA
//   (mi-half x ks quadrant) ; setprio(0) ; [vmcnt(6) at ph4/ph8] ; barrier}
// - stage rotation (iter t,t+1): ph1:A(t+1)k1->b1, ph2:B(t+2)k0->b0,
//   ph3:A(t+2)k0, ph4:B(t+2)k1, ph5:A(t+2)k1, ph6:B(t+3)k0->b1,
//   ph7:A(t+3)k0, ph8:B(t+3)k1.  Each stage lands in a region whose last
//   read was the previous phase (barrier-separated).  vmcnt(6) at ph4
//   drains all of tile t+1 (before ph5 reads it); at ph8 drains all of
//   t+2 (before next iter's ph1).  3 half-tiles stay in flight, never 0.
// - bank swizzle within half: slot' = slot ^ ((row>>1)&3)  (2 lanes/bank =
//   free, m136); inverse applied to the global source (rule #21).
// EPI: 0 -> outBf = bf16(acc*scale)                              (S)
//      1 -> outBf = bf16(bf2f(auxBf) + acc)                      (X = Q + PV)
//      2 -> outBf = bf16(relu(acc + bias[col]))                  (FFN1 -> h)
//      3 -> outF  = acc + bias[col] + bf2f(auxBf)                (FFN2 + residual)
#define MFMA16(a, b, c) __builtin_amdgcn_mfma_f32_16x16x32_bf16(a, b, c, 0, 0, 0)

#define CL16(H)                                                   \
  acc[(H)*4+0][0] = MFMA16(a0, b0, acc[(H)*4+0][0]);              \
  acc[(H)*4+0][1] = MFMA16(a0, b1, acc[(H)*4+0][1]);              \
  acc[(H)*4+0][2] = MFMA16(a0, b2, acc[(H)*4+0][2]);              \
  acc[(H)*4+0][3] = MFMA16(a0, b3, acc[(H)*4+0][3]);              \
  acc[(H)*4+1][0] = MFMA16(a1, b0, acc[(H)*4+1][0]);              \
  acc[(H)*4+1][1] = MFMA16(a1, b1, acc[(H)*4+1][1]);              \
  acc[(H)*4+1][2] = MFMA16(a1, b2, acc[(H)*4+1][2]);              \
  acc[(H)*4+1][3] = MFMA16(a1, b3, acc[(H)*4+1][3]);              \
  acc[(H)*4+2][0] = MFMA16(a2, b0, acc[(H)*4+2][0]);              \
  acc[(H)*4+2][1] = MFMA16(a2, b1, acc[(H)*4+2][1]);              \
  acc[(H)*4+2][2] = MFMA16(a2, b2, acc[(H)*4+2][2]);              \
  acc[(H)*4+2][3] = MFMA16(a2, b3, acc[(H)*4+2][3]);              \
  acc[(H)*4+3][0] = MFMA16(a3, b0, acc[(H)*4+3][0]);              \
  acc[(H)*4+3][1] = MFMA16(a3, b1, acc[(H)*4+3][1]);              \
  acc[(H)*4+3][2] = MFMA16(a3, b2, acc[(H)*4+3][2]);              \
  acc[(H)*4+3][3] = MFMA16(a3, b3, acc[(H)*4+3][3]);

#define PH_TAIL(H, DOVM)                                          \
  __builtin_amdgcn_s_barrier();                                   \
  asm volatile("s_waitcnt lgkmcnt(0)" ::: "memory");              \
  __builtin_amdgcn_sched_barrier(0);                              \
  __builtin_amdgcn_s_setprio(1);                                  \
  CL16(H)                                                         \
  __builtin_amdgcn_s_setprio(0);                                  \
  if (DOVM) { asm volatile("s_waitcnt vmcnt(6)" ::: "memory"); }  \
  __builtin_amdgcn_s_barrier();

template<int EPI>
__global__ __launch_bounds__(512, 2)
void gemm256(const ushort* __restrict__ A, const ushort* __restrict__ Bt,
             size_t aBatch, size_t bBatch, size_t oBatch,
             float scale,
             ushort* outBf, float* outF, const ushort* auxBf,
             const float* __restrict__ bias)
{
  constexpr int K = 1024, N = 1024, NT = 16;    // K-tiles of 64
  __shared__ ushort lds[2][2][2][8192];         // [buf][A,B][ksHalf][256r x 32K] = 128 KiB
  const int t = threadIdx.x;
  const int w = t >> 6, lane = t & 63;
  const int wr = w >> 2, wc = w & 3;            // 2 x 4 waves -> 128x64 per wave
  const int lr16 = lane & 15, kg = lane >> 4;   // kg = K-slot 0..3 within half

  // T1: XCD-aware bijective remap (nwg is a multiple of 8 for all our grids)
  const unsigned nx = gridDim.x, ny = gridDim.y;
  unsigned flat = blockIdx.x + nx * (blockIdx.y + ny * blockIdx.z);
  const unsigned nwg = nx * ny * gridDim.z;
  const unsigned cpx = nwg >> 3;
  unsigned nf = (flat & 7u) * cpx + (flat >> 3);
  const unsigned bxi = nf % nx;
  const unsigned rest = nf / nx;
  const unsigned byi = rest % ny;
  const unsigned bz = rest / ny;
  const int m0 = byi * 256, n0 = bxi * 256;

  const char* Ab = (const char*)(A + (size_t)bz * aBatch + (size_t)m0 * K);
  const char* Bb = (const char*)(Bt + (size_t)bz * bBatch + (size_t)n0 * K);

  // staging decode: half-tile = 16 KB; thread stages 2 chunks of 16 B.
  // linear y = c*8192 + w*1024 + lane*16 ; r = y>>6, s = (y>>4)&3 ;
  // tile slot s_tile = s ^ ((r>>1)&3) ; global = r*2048 + s_tile*16
  // (+ kt*128 + ksHalf*64 at stage time).
  int gBase[2], lBase[2];
  #pragma unroll
  for (int c = 0; c < 2; ++c) {
    int y = c * 8192 + w * 1024 + lane * 16;
    int r = y >> 6, s = (y >> 4) & 3;
    gBase[c] = r * 2048 + ((s ^ ((r >> 1) & 3)) << 4);
    lBase[c] = c * 8192 + w * 1024;             // wave-uniform (+lane*16 by HW)
  }
  auto STG = [&](int buf, int mat, int ks, int kt, const char* Gb) {
    char* dst = (char*)&lds[buf][mat][ks][0];
    #pragma unroll
    for (int c = 0; c < 2; ++c)
      __builtin_amdgcn_global_load_lds(
        (const AS1 void*)(Gb + gBase[c] + kt * 128 + ks * 64),
        (AS3 void*)(dst + lBase[c]), 16, 0, 0);
  };

  // fragment reads: row R = base + mi*16 + lr16 (64 B rows within half);
  // slot = kg ^ ((lr16>>1)&3)  (same for all mi/ni: base multiples of 8 rows)
  const int slt = (kg ^ ((lr16 >> 1) & 3)) << 4;
  const int aOff0 = (wr * 128 + lr16) * 64 + slt;
  const int bOff0 = (wc * 64 + lr16) * 64 + slt;
  auto LDA = [&](int buf, int ks, int mi) -> bf16x8 {
    return *(const bf16x8*)((const char*)&lds[buf][0][ks][0] + aOff0 + mi * 1024);
  };
  auto LDB = [&](int buf, int ks, int ni) -> bf16x8 {
    return *(const bf16x8*)((const char*)&lds[buf][1][ks][0] + bOff0 + ni * 1024);
  };

  f32x4 acc[8][4];
  #pragma unroll
  for (int i = 0; i < 8; ++i)
    #pragma unroll
    for (int j = 0; j < 4; ++j)
      acc[i][j] = (f32x4){0.f, 0.f, 0.f, 0.f};

  // prologue: replicate steady-state (prev ph2..ph8): stage t0 fully +
  // 3 halves of t1; vmcnt(6) drains t0, leaves t1's 3 halves in flight.
  STG(0, 1, 0, 0, Bb);  STG(0, 0, 0, 0, Ab);
  STG(0, 1, 1, 0, Bb);  STG(0, 0, 1, 0, Ab);
  STG(1, 1, 0, 1, Bb);  STG(1, 0, 0, 1, Ab);
  STG(1, 1, 1, 1, Bb);
  asm volatile("s_waitcnt vmcnt(6)" ::: "memory");
  __builtin_amdgcn_s_barrier();

  #pragma unroll 1
  for (int it = 0; it < NT / 2; ++it) {
    const int tt = 2 * it;
    const int t2 = tt + 2 < NT ? tt + 2 : NT - 1;   // clamped tails: dummy
    const int t3 = tt + 3 < NT ? tt + 3 : NT - 1;   // re-stages, regions dead
    bf16x8 a0, a1, a2, a3, b0, b1, b2, b3;

    // ph1: buf0 ks0, A-lo + B ; stage A(t+1)ks1 -> buf1
    a0 = LDA(0,0,0); a1 = LDA(0,0,1); a2 = LDA(0,0,2); a3 = LDA(0,0,3);
    b0 = LDB(0,0,0); b1 = LDB(0,0,1); b2 = LDB(0,0,2); b3 = LDB(0,0,3);
    STG(1, 0, 1, tt + 1, Ab);
    PH_TAIL(0, false)
    // ph2: buf0 ks0, A-hi ; stage B(t+2)ks0 -> buf0
    a0 = LDA(0,0,4); a1 = LDA(0,0,5); a2 = LDA(0,0,6); a3 = LDA(0,0,7);
    STG(0, 1, 0, t2, Bb);
    PH_TAIL(1, false)
    // ph3: buf0 ks1, A-lo + B ; stage A(t+2)ks0 -> buf0
    a0 = LDA(0,1,0); a1 = LDA(0,1,1); a2 = LDA(0,1,2); a3 = LDA(0,1,3);
    b0 = LDB(0,1,0); b1 = LDB(0,1,1); b2 = LDB(0,1,2); b3 = LDB(0,1,3);
    STG(0, 0, 0, t2, Ab);
    PH_TAIL(0, false)
    // ph4: buf0 ks1, A-hi ; stage B(t+2)ks1 -> buf0 ; vmcnt(6)
    a0 = LDA(0,1,4); a1 = LDA(0,1,5); a2 = LDA(0,1,6); a3 = LDA(0,1,7);
    STG(0, 1, 1, t2, Bb);
    PH_TAIL(1, true)
    // ph5: buf1 ks0, A-lo + B ; stage A(t+2)ks1 -> buf0
    a0 = LDA(1,0,0); a1 = LDA(1,0,1); a2 = LDA(1,0,2); a3 = LDA(1,0,3);
    b0 = LDB(1,0,0); b1 = LDB(1,0,1); b2 = LDB(1,0,2); b3 = LDB(1,0,3);
    STG(0, 0, 1, t2, Ab);
    PH_TAIL(0, false)
    // ph6: buf1 ks0, A-hi ; stage B(t+3)ks0 -> buf1
    a0 = LDA(1,0,4); a1 = LDA(1,0,5); a2 = LDA(1,0,6); a3 = LDA(1,0,7);
    STG(1, 1, 0, t3, Bb);
    PH_TAIL(1, false)
    // ph7: buf1 ks1, A-lo + B ; stage A(t+3)ks0 -> buf1
    a0 = LDA(1,1,0); a1 = LDA(1,1,1); a2 = LDA(1,1,2); a3 = LDA(1,1,3);
    b0 = LDB(1,1,0); b1 = LDB(1,1,1); b2 = LDB(1,1,2); b3 = LDB(1,1,3);
    STG(1, 0, 0, t3, Ab);
    PH_TAIL(0, false)
    // ph8: buf1 ks1, A-hi ; stage B(t+3)ks1 -> buf1 ; vmcnt(6)
    a0 = LDA(1,1,4); a1 = LDA(1,1,5); a2 = LDA(1,1,6); a3 = LDA(1,1,7);
    STG(1, 1, 1, t3, Bb);
    PH_TAIL(1, true)
  }

  // epilogue: C/D layout col=lane&15, row=(lane>>4)*4+j  [m89-verified]
  const int lr4 = kg * 4;
  #pragma unroll
  for (int mi = 0; mi < 8; ++mi) {
    #pragma unroll
    for (int ni = 0; ni < 4; ++ni) {
      int row = m0 + wr * 128 + mi * 16 + lr4;
      int col = n0 + wc * 64 + ni * 16 + lr16;
      size_t o = (size_t)bz * oBatch + (size_t)row * N + col;
      f32x4 v = acc[mi][ni];
      #pragma unroll
      for (int j = 0; j < 4; ++j) {
        size_t oo = o + (size_t)j * N;
        float x = v[j];
        if (EPI == 0) {
          outBf[oo] = f2bf(x * scale);
        } else if (EPI == 1) {
          outBf[oo] = f2bf(bf2f(auxBf[oo]) + x);
        } else if (EPI == 2) {
          float h = x + bias[col];
          h = h > 0.f ? h : 0.f;
          outBf[oo] = f2bf(h);
        } else {
          outF[oo] = x + bias[col] + bf2f(auxBf[oo]);
        }
      }
    }
  }
}

// ---------------- launch ----------------
extern "C" void kernel_launch(void* const* d_in, const int* in_sizes, int n_in,
                              void* d_out, int out_size, void* d_ws, size_t ws_size,
                              hipStream_t stream) {
  (void)in_sizes; (void)n_in; (void)out_size; (void)ws_size;
  const float* Q  = (const float*)d_in[0];
  const float* Km = (const float*)d_in[1];
  const float* V  = (const float*)d_in[2];
  const float* Vm = (const float*)d_in[3];
  const float* W1 = (const float*)d_in[4];
  const float* b1 = (const float*)d_in[5];
  const float* W2 = (const float*)d_in[6];
  const float* b2 = (const float*)d_in[7];
  float* out = (float*)d_out;

  const int LQ = 1024, LK = 1024, D = 1024;
  const size_t NQ = (size_t)32 * LQ * D;            // 33.5M elems

  // workspace layout (MiB offsets): Qb 0..64, Kb/hb 64..128, Vt 128..192,
  // Sb 192..256, P 256..320, Xb 320..384, W1b 384..386, W2b 386..388
  char* ws = (char*)d_ws;
  ushort* Qb  = (ushort*)(ws);
  ushort* Kb  = (ushort*)(ws + ((size_t)64 << 20));
  ushort* hb  = Kb;                                  // reuse (Kb dead after S-GEMM)
  ushort* Vt  = (ushort*)(ws + ((size_t)128 << 20));
  ushort* Sb  = (ushort*)(ws + ((size_t)192 << 20));
  ushort* P   = (ushort*)(ws + ((size_t)256 << 20));
  ushort* Xb  = (ushort*)(ws + ((size_t)320 << 20));
  ushort* W1b = (ushort*)(ws + ((size_t)384 << 20));
  ushort* W2b = (ushort*)(ws + ((size_t)386 << 20));

  const float inv_scale = 1.0f / (sqrtf(1024.0f) + 1e-8f);

  cast_f32_bf16<<<2048, 256, 0, stream>>>((const float4*)Q,  (ushort4*)Qb, (int)(NQ / 4));
  cast_f32_bf16<<<2048, 256, 0, stream>>>((const float4*)Km, (ushort4*)Kb, (int)(NQ / 4));
  cast_f32_bf16<<<256, 256, 0, stream>>>((const float4*)W1, (ushort4*)W1b, (1024 * 1024) / 4);
  cast_f32_bf16<<<256, 256, 0, stream>>>((const float4*)W2, (ushort4*)W2b, (1024 * 1024) / 4);
  transpose_cast_v<<<dim3(32, 32, 32), dim3(32, 8), 0, stream>>>(V, Vt);

  // Sb = bf16((Qb @ Kb^T) * inv_scale), batched over 32
  gemm256<0><<<dim3(4, 4, 32), 512, 0, stream>>>(
      Qb, Kb,
      (size_t)LQ * D, (size_t)LK * D, (size_t)LQ * LK,
      inv_scale, Sb, nullptr, nullptr, nullptr);

  softmax_mask<<<32768, 256, 0, stream>>>(Sb, P, Vm);

  // Xb = bf16(Qb + P @ V)
  gemm256<1><<<dim3(4, 4, 32), 512, 0, stream>>>(
      P, Vt,
      (size_t)LQ * LK, (size_t)D * LK, (size_t)LQ * D,
      1.f, Xb, nullptr, Qb, nullptr);

  // hb = bf16(relu(Xb @ W1^T + b1)); M = 32768 folded into blockIdx.y
  gemm256<2><<<dim3(4, 128, 1), 512, 0, stream>>>(
      Xb, W1b, 0, 0, 0,
      1.f, hb, nullptr, nullptr, b1);

  // out = hb @ W2^T + b2 + Xb
  gemm256<3><<<dim3(4, 128, 1), 512, 0, stream>>>(
      hb, W2b, 0, 0, 0,
      1.f, nullptr, out, Xb, b2);
}